// Round 5
// baseline (144.544 us; speedup 1.0000x reference)
//
#include <hip/hip_runtime.h>
#include <math.h>

#define BATCH 128
#define NNODE 512
#define RU 64
#define MEM_DIM 16
#define BOT_DIM 4
#define IN_SZ 66
#define OUT_SZ 256
#define HID (NNODE*RU)          // 32768
#define W3_ROW 16896            // IN_SZ*OUT_SZ
// W_ws layout: [node][half h][frag fl=(ctl*3+ks)][lane][8 bf16]
//   = n*24576 + h*12288 + fl*512 + lane*8   (shorts). 48 KB/node, 24.6 MB total.
#define NODE_WS 24576
#define HALF_WS 12288

typedef __attribute__((ext_vector_type(8))) short short8;
typedef __attribute__((ext_vector_type(4))) float float4v;

__device__ __forceinline__ unsigned short f2bf(float f) {
    unsigned int u = __float_as_uint(f);
    unsigned int r = (u + 0x7FFFu + ((u >> 16) & 1u)) >> 16;
    return (unsigned short)r;
}
__device__ __forceinline__ float fsig(float x) {
    return __builtin_amdgcn_rcpf(1.0f + __expf(-x));
}
__device__ __forceinline__ float ftanh(float x) {
    return 1.0f - 2.0f * __builtin_amdgcn_rcpf(1.0f + __expf(2.0f * x));
}

// ---------------- Kernel 1: W materialization, LDS-free, frag-order output ----
// block = (npair, h, fg): 2 nodes x 12 frags x 64 lanes = 1536 chunks / 256 thr.
// Chunk (fl, l): col c = h*128 + ctl*16 + (l&15); slots s = ks*32 + (l>>4)*8 + j.
// Slot->W row: s<64 -> i=s+2 ; s=64,65 -> i=s-64 ; s>=66 -> zero pad.
__global__ __launch_bounds__(256) void wgen_kernel(
    const float* __restrict__ memory, const float* __restrict__ w1,
    const float* __restrict__ b1,     const float* __restrict__ w2,
    const float* __restrict__ b2,     const float* __restrict__ w3,
    const float* __restrict__ b3,     unsigned short* __restrict__ W_ws)
{
    __shared__ float mem1s[2][MEM_DIM];
    __shared__ float m2s[2][BOT_DIM];

    const int tid   = threadIdx.x;
    const unsigned bid = blockIdx.x;
    const int npair = bid >> 2;
    const int h     = (bid >> 1) & 1;
    const int fg    = bid & 1;
    const int n0    = npair * 2;

    if (tid < 32) {
        int nn = tid >> 4, t = tid & 15;
        float s = b1[t];
        #pragma unroll
        for (int j = 0; j < MEM_DIM; ++j)
            s += memory[(n0 + nn) * MEM_DIM + j] * w1[j * MEM_DIM + t];
        mem1s[nn][t] = ftanh(s);
    }
    __syncthreads();
    if (tid < 8) {
        int nn = tid >> 2, t = tid & 3;
        float s = b2[t];
        #pragma unroll
        for (int j = 0; j < MEM_DIM; ++j)
            s += mem1s[nn][j] * w2[j * BOT_DIM + t];
        m2s[nn][t] = ftanh(s);
    }
    __syncthreads();

    float ma[4], mb[4];
    #pragma unroll
    for (int k = 0; k < 4; ++k) { ma[k] = m2s[0][k]; mb[k] = m2s[1][k]; }

    unsigned short* dst0 = W_ws + (size_t)n0 * NODE_WS + h * HALF_WS;
    unsigned short* dst1 = dst0 + NODE_WS;

    #pragma unroll 2
    for (int it = 0; it < 6; ++it) {
        const int cid = it * 256 + tid;          // [0,1536)
        const int fl  = fg * 12 + (cid >> 6);    // frag index in half, [0,24)
        const int l   = cid & 63;
        const int ctl = fl / 3;
        const int ks  = fl - ctl * 3;
        const int q = l & 15, quad = l >> 4;
        const int ct = h * 8 + ctl;
        const int o  = (ct & 3) * 64 + ((ct >> 2) << 4) + q;

        short8 va, vb;
        #pragma unroll
        for (int j = 0; j < 8; ++j) {
            const int s = ks * 32 + quad * 8 + j;
            float r0 = 0.f, r1 = 0.f;
            if (s < IN_SZ) {
                const int i = (s < 64) ? s + 2 : s - 64;
                const int base = i * OUT_SZ + o;
                float bb = b3[base];
                float x0 = w3[base];
                float x1 = w3[W3_ROW + base];
                float x2 = w3[2 * W3_ROW + base];
                float x3 = w3[3 * W3_ROW + base];
                r0 = bb + ma[0] * x0 + ma[1] * x1 + ma[2] * x2 + ma[3] * x3;
                r1 = bb + mb[0] * x0 + mb[1] * x1 + mb[2] * x2 + mb[3] * x3;
            }
            va[j] = (short)f2bf(r0);
            vb[j] = (short)f2bf(r1);
        }
        const int off = fl * 512 + l * 8;
        *(short8*)(dst0 + off) = va;    // consecutive threads -> contiguous 16B
        *(short8*)(dst1 + off) = vb;
    }
}

// ---------------- Kernel 2: MFMA GEMM + LSTM epilogue, LDS-free, barrier-free --
// block = (n, qh): col-quarter qh -> ct = qh*4 + ctl' -> gate g = ctl', r = qh*16+q.
__global__ __launch_bounds__(256, 4) void gemm_kernel(
    const float* __restrict__ inputs, const float* __restrict__ hx,
    const float* __restrict__ cx,     const float* __restrict__ b_out,
    const unsigned short* __restrict__ W_ws, float* __restrict__ out)
{
    const int tid  = threadIdx.x;
    const unsigned bid = blockIdx.x;
    const int n    = bid >> 2;
    const int qh   = bid & 3;
    const int w    = tid >> 6;
    const int lane = tid & 63;
    const int q    = lane & 15;
    const int quad = lane >> 4;

    // this block's 12 B-fragments (1KB each, coalesced, L1-shared by the 4 waves)
    const unsigned short* Wb = W_ws + (size_t)n * NODE_WS + (qh >> 1) * HALF_WS
                             + (qh & 1) * 4 * 3 * 512;

    // A-fragments from hx/inputs
    short8 a[3][2];
    #pragma unroll
    for (int rt = 0; rt < 2; ++rt) {
        const int row = w * 32 + rt * 16 + q;
        const float* hrow = hx + (size_t)row * HID + n * RU + quad * 8;
        #pragma unroll
        for (int ks = 0; ks < 2; ++ks) {
            float4v f0 = *(const float4v*)(hrow + ks * 32);
            float4v f1 = *(const float4v*)(hrow + ks * 32 + 4);
            short8 t;
            t[0] = (short)f2bf(f0[0]); t[1] = (short)f2bf(f0[1]);
            t[2] = (short)f2bf(f0[2]); t[3] = (short)f2bf(f0[3]);
            t[4] = (short)f2bf(f1[0]); t[5] = (short)f2bf(f1[1]);
            t[6] = (short)f2bf(f1[2]); t[7] = (short)f2bf(f1[3]);
            a[ks][rt] = t;
        }
        short8 t2 = {0, 0, 0, 0, 0, 0, 0, 0};
        if (quad == 0) {   // k-slots 64,65 = this node's two raw inputs (ks=2)
            const float* ip = inputs + (size_t)row * (NNODE * 2) + n * 2;
            t2[0] = (short)f2bf(ip[0]);
            t2[1] = (short)f2bf(ip[1]);
        }
        a[2][rt] = t2;
    }

    const int r = qh * 16 + q;            // this lane's r within the node
    float bo[4];
    #pragma unroll
    for (int g = 0; g < 4; ++g) bo[g] = b_out[g * 64 + r];

    float cxr[2][4];
    #pragma unroll
    for (int rt = 0; rt < 2; ++rt)
        #pragma unroll
        for (int v = 0; v < 4; ++v) {
            const int b = w * 32 + rt * 16 + quad * 4 + v;
            cxr[rt][v] = cx[(size_t)b * HID + n * RU + r];
        }

    float4v acc[2][4];
    #pragma unroll
    for (int rt = 0; rt < 2; ++rt)
        #pragma unroll
        for (int g = 0; g < 4; ++g)
            acc[rt][g] = (float4v){0.f, 0.f, 0.f, 0.f};

    #pragma unroll
    for (int ks = 0; ks < 3; ++ks) {
        #pragma unroll
        for (int g = 0; g < 4; ++g) {
            short8 bf = *(const short8*)(Wb + (g * 3 + ks) * 512 + lane * 8);
            acc[0][g] = __builtin_amdgcn_mfma_f32_16x16x32_bf16(a[ks][0], bf, acc[0][g], 0, 0, 0);
            acc[1][g] = __builtin_amdgcn_mfma_f32_16x16x32_bf16(a[ks][1], bf, acc[1][g], 0, 0, 0);
        }
    }

    // LSTM epilogue: gate g = acc[rt][g][v] for (b, r)
    #pragma unroll
    for (int rt = 0; rt < 2; ++rt) {
        #pragma unroll
        for (int v = 0; v < 4; ++v) {
            const int b = w * 32 + rt * 16 + quad * 4 + v;
            const size_t idx = (size_t)b * HID + n * RU + r;
            // reference: val = sigmoid(matmul) + b_out, THEN gate activations
            float vi = fsig(acc[rt][0][v]) + bo[0];
            float vf = fsig(acc[rt][1][v]) + bo[1];
            float vg = fsig(acc[rt][2][v]) + bo[2];
            float vo = fsig(acc[rt][3][v]) + bo[3];
            float it = fsig(vi), ft = fsig(vf);
            float gt = ftanh(vg), ot = fsig(vo);
            float cc = cxr[rt][v] * ft + it * gt;
            out[idx] = ot * ftanh(cc);               // hy
            out[(size_t)BATCH * HID + idx] = cc;     // cy
        }
    }
}

extern "C" void kernel_launch(void* const* d_in, const int* in_sizes, int n_in,
                              void* d_out, int out_size, void* d_ws, size_t ws_size,
                              hipStream_t stream) {
    const float* inputs = (const float*)d_in[0];
    const float* hx     = (const float*)d_in[1];
    const float* cx     = (const float*)d_in[2];
    const float* memory = (const float*)d_in[3];
    const float* w1     = (const float*)d_in[4];
    const float* b1     = (const float*)d_in[5];
    const float* w2     = (const float*)d_in[6];
    const float* b2     = (const float*)d_in[7];
    const float* w3     = (const float*)d_in[8];
    const float* b3     = (const float*)d_in[9];
    const float* b_out  = (const float*)d_in[10];
    float* out = (float*)d_out;

    unsigned short* W_ws = (unsigned short*)d_ws;   // 24.6 MB

    wgen_kernel<<<256 * 4, 256, 0, stream>>>(memory, w1, b1, w2, b2, w3, b3, W_ws);
    gemm_kernel<<<NNODE * 4, 256, 0, stream>>>(inputs, hx, cx, b_out, W_ws, out);
}

// Round 6
// 138.057 us; speedup vs baseline: 1.0470x; 1.0470x over previous
//
#include <hip/hip_runtime.h>
#include <math.h>

#define BATCH 128
#define NNODE 512
#define RU 64
#define MEM_DIM 16
#define BOT_DIM 4
#define IN_SZ 66
#define OUT_SZ 256
#define HID (NNODE*RU)          // 32768
#define W3_ROW 16896            // IN_SZ*OUT_SZ
// W5 table: 5 matrices (w3_0..3, b3) in MFMA B-frag order, bf16.
// frag f = (k*16 + ct)*3 + ks ; element = lane*8 + j  (short8 per lane)
// col o = (ct&3)*64 + (ct>>2)*16 + (lane&15)
// slot s = ks*32 + (lane>>4)*8 + j ; s<64 -> i=s+2 ; s=64,65 -> i=0,1 ; else 0
#define W5_BYTES (240*512*2)    // 245760 B

typedef __attribute__((ext_vector_type(8))) short short8;
typedef __attribute__((ext_vector_type(4))) float float4v;

__device__ __forceinline__ unsigned short f2bf(float f) {
    unsigned int u = __float_as_uint(f);
    unsigned int r = (u + 0x7FFFu + ((u >> 16) & 1u)) >> 16;
    return (unsigned short)r;
}
__device__ __forceinline__ float fsig(float x) {
    return __builtin_amdgcn_rcpf(1.0f + __expf(-x));
}
__device__ __forceinline__ float ftanh(float x) {
    return 1.0f - 2.0f * __builtin_amdgcn_rcpf(1.0f + __expf(2.0f * x));
}

// ---------------- Kernel 1: prep — W5 table (bf16 frag order) + hypernet m2 ----
__global__ __launch_bounds__(256) void prep_kernel(
    const float* __restrict__ memory, const float* __restrict__ w1,
    const float* __restrict__ b1,     const float* __restrict__ w2,
    const float* __restrict__ b2,     const float* __restrict__ w3,
    const float* __restrict__ b3,     unsigned short* __restrict__ W5,
    float* __restrict__ m2_ws)
{
    const int tid = threadIdx.x;
    const int bid = blockIdx.x;
    if (bid < 60) {
        const int c    = bid * 256 + tid;    // [0, 15360) lane-chunks
        const int lane = c & 63;
        const int f    = c >> 6;             // [0, 240)
        const int ks   = f % 3;
        const int t2   = f / 3;              // [0, 80)
        const int ct   = t2 & 15;
        const int k    = t2 >> 4;            // [0, 5)
        const int q = lane & 15, quad = lane >> 4;
        const int o = (ct & 3) * 64 + (ct >> 2) * 16 + q;
        const float* src = (k < 4) ? (w3 + k * W3_ROW) : b3;
        short8 v;
        #pragma unroll
        for (int j = 0; j < 8; ++j) {
            const int s = ks * 32 + quad * 8 + j;
            float x = 0.f;
            if (s < IN_SZ) {
                const int i = (s < 64) ? s + 2 : s - 64;
                x = src[i * OUT_SZ + o];
            }
            v[j] = (short)f2bf(x);
        }
        *(short8*)(W5 + f * 512 + lane * 8) = v;
    } else {
        const int n = (bid - 60) * 256 + tid;   // [0, 512)
        if (n < NNODE) {
            float memv[MEM_DIM];
            #pragma unroll
            for (int j = 0; j < MEM_DIM; ++j) memv[j] = memory[n * MEM_DIM + j];
            float mem1[MEM_DIM];
            #pragma unroll
            for (int t = 0; t < MEM_DIM; ++t) {
                float s = b1[t];
                #pragma unroll
                for (int j = 0; j < MEM_DIM; ++j) s += memv[j] * w1[j * MEM_DIM + t];
                mem1[t] = ftanh(s);
            }
            #pragma unroll
            for (int t = 0; t < BOT_DIM; ++t) {
                float s = b2[t];
                #pragma unroll
                for (int j = 0; j < MEM_DIM; ++j) s += mem1[j] * w2[j * BOT_DIM + t];
                m2_ws[n * 4 + t] = ftanh(s);
            }
        }
    }
}

// ---------------- Kernel 2: fused GEMM (coef folded into A) + LSTM epilogue ----
// grid = 512 nodes; 512 threads = 8 waves = (row-half rh) x (quarter qh).
// Wave tile: 64 batch rows x 64 cols (4 gates x 16 r). No LDS, no barriers.
__global__ __launch_bounds__(512, 2) void fused_kernel(
    const float* __restrict__ inputs, const float* __restrict__ hx,
    const float* __restrict__ cx,     const float* __restrict__ b_out,
    const unsigned short* __restrict__ W5, const float* __restrict__ m2_ws,
    float* __restrict__ out)
{
    const int tid  = threadIdx.x;
    const int n    = blockIdx.x;
    const int w    = tid >> 6;
    const int lane = tid & 63;
    const int rh   = w >> 2;
    const int qh   = w & 3;
    const int q    = lane & 15;
    const int quad = lane >> 4;

    float coef[5];
    #pragma unroll
    for (int k = 0; k < 4; ++k) coef[k] = m2_ws[n * 4 + k];
    coef[4] = 1.0f;

    // xs fp32: 4 row-tiles x (16 h-values + 2 inputs) per lane
    float4v xa[4][4];        // [rt][ks0_lo, ks0_hi, ks1_lo, ks1_hi]
    float xin[4][2];
    #pragma unroll
    for (int rt = 0; rt < 4; ++rt) {
        const int row = rh * 64 + rt * 16 + q;
        const float* hrow = hx + (size_t)row * HID + n * RU + quad * 8;
        xa[rt][0] = *(const float4v*)(hrow);
        xa[rt][1] = *(const float4v*)(hrow + 4);
        xa[rt][2] = *(const float4v*)(hrow + 32);
        xa[rt][3] = *(const float4v*)(hrow + 36);
        if (quad == 0) {
            const float* ip = inputs + (size_t)row * (NNODE * 2) + n * 2;
            xin[rt][0] = ip[0];
            xin[rt][1] = ip[1];
        } else {
            xin[rt][0] = 0.f;
            xin[rt][1] = 0.f;
        }
    }

    // epilogue operands prefetch
    const int r = qh * 16 + q;
    float bo[4];
    #pragma unroll
    for (int g = 0; g < 4; ++g) bo[g] = b_out[g * 64 + r];
    float cxr[4][4];
    #pragma unroll
    for (int rt = 0; rt < 4; ++rt)
        #pragma unroll
        for (int v = 0; v < 4; ++v) {
            const int b = rh * 64 + rt * 16 + quad * 4 + v;
            cxr[rt][v] = cx[(size_t)b * HID + n * RU + r];
        }

    float4v acc[4][4];       // [rt][gate]
    #pragma unroll
    for (int rt = 0; rt < 4; ++rt)
        #pragma unroll
        for (int g = 0; g < 4; ++g)
            acc[rt][g] = (float4v){0.f, 0.f, 0.f, 0.f};

    // main loop: acc += sum_k (coef_k * xs) @ w3_k   (k=4 is the b3 matrix, coef 1)
    #pragma unroll
    for (int k = 0; k < 5; ++k) {
        const float cf = coef[k];
        short8 af[3][4];
        #pragma unroll
        for (int rt = 0; rt < 4; ++rt) {
            #pragma unroll
            for (int ksh = 0; ksh < 2; ++ksh) {
                float4v lo = xa[rt][ksh * 2];
                float4v hi = xa[rt][ksh * 2 + 1];
                if (k < 4) { lo *= cf; hi *= cf; }
                short8 t;
                t[0] = (short)f2bf(lo[0]); t[1] = (short)f2bf(lo[1]);
                t[2] = (short)f2bf(lo[2]); t[3] = (short)f2bf(lo[3]);
                t[4] = (short)f2bf(hi[0]); t[5] = (short)f2bf(hi[1]);
                t[6] = (short)f2bf(hi[2]); t[7] = (short)f2bf(hi[3]);
                af[ksh][rt] = t;
            }
            float a0 = xin[rt][0], a1 = xin[rt][1];
            if (k < 4) { a0 *= cf; a1 *= cf; }
            short8 t2 = {0, 0, 0, 0, 0, 0, 0, 0};
            t2[0] = (short)f2bf(a0);
            t2[1] = (short)f2bf(a1);
            af[2][rt] = t2;
        }
        #pragma unroll
        for (int ks = 0; ks < 3; ++ks)
            #pragma unroll
            for (int g = 0; g < 4; ++g) {
                const short8 bf = *(const short8*)(
                    W5 + (size_t)((k * 16 + qh * 4 + g) * 3 + ks) * 512 + lane * 8);
                #pragma unroll
                for (int rt = 0; rt < 4; ++rt)
                    acc[rt][g] = __builtin_amdgcn_mfma_f32_16x16x32_bf16(
                        af[ks][rt], bf, acc[rt][g], 0, 0, 0);
            }
    }

    // LSTM epilogue — all 4 gates of (b, r) in one lane
    #pragma unroll
    for (int rt = 0; rt < 4; ++rt) {
        #pragma unroll
        for (int v = 0; v < 4; ++v) {
            const int b = rh * 64 + rt * 16 + quad * 4 + v;
            const size_t idx = (size_t)b * HID + n * RU + r;
            // reference: val = sigmoid(matmul) + b_out, THEN gate activations
            float vi = fsig(acc[rt][0][v]) + bo[0];
            float vf = fsig(acc[rt][1][v]) + bo[1];
            float vg = fsig(acc[rt][2][v]) + bo[2];
            float vo = fsig(acc[rt][3][v]) + bo[3];
            float it = fsig(vi), ft = fsig(vf);
            float gt = ftanh(vg), ot = fsig(vo);
            float cc = cxr[rt][v] * ft + it * gt;
            out[idx] = ot * ftanh(cc);               // hy
            out[(size_t)BATCH * HID + idx] = cc;     // cy
        }
    }
}

extern "C" void kernel_launch(void* const* d_in, const int* in_sizes, int n_in,
                              void* d_out, int out_size, void* d_ws, size_t ws_size,
                              hipStream_t stream) {
    const float* inputs = (const float*)d_in[0];
    const float* hx     = (const float*)d_in[1];
    const float* cx     = (const float*)d_in[2];
    const float* memory = (const float*)d_in[3];
    const float* w1     = (const float*)d_in[4];
    const float* b1     = (const float*)d_in[5];
    const float* w2     = (const float*)d_in[6];
    const float* b2     = (const float*)d_in[7];
    const float* w3     = (const float*)d_in[8];
    const float* b3     = (const float*)d_in[9];
    const float* b_out  = (const float*)d_in[10];
    float* out = (float*)d_out;

    unsigned short* W5 = (unsigned short*)d_ws;
    float* m2_ws = (float*)((char*)d_ws + W5_BYTES);

    prep_kernel<<<62, 256, 0, stream>>>(memory, w1, b1, w2, b2, w3, b3, W5, m2_ws);
    fused_kernel<<<NNODE, 512, 0, stream>>>(inputs, hx, cx, b_out, W5, m2_ws, out);
}

// Round 7
// 126.785 us; speedup vs baseline: 1.1401x; 1.0889x over previous
//
#include <hip/hip_runtime.h>
#include <math.h>

#define BATCH 128
#define NNODE 512
#define RU 64
#define MEM_DIM 16
#define BOT_DIM 4
#define IN_SZ 66
#define OUT_SZ 256
#define HID (NNODE*RU)          // 32768
#define W3_ROW 16896            // IN_SZ*OUT_SZ
// W5f table: 5 matrices (w3_0..3, b3) in MFMA B-frag order, fp32.
// frag f = (k*16 + ct)*3 + ks ; float idx = f*512 + lane*8 + j
// col o = (ct&3)*64 + (ct>>2)*16 + (lane&15)
// slot s = ks*32 + (lane>>4)*8 + j ; s<64 -> i=s+2 ; s=64,65 -> i=0,1 ; else 0
#define W5F_FLOATS (240*512)    // 122880 floats = 491520 B
#define K_STEP 24576            // (16*3*512) floats between k-matrices

typedef __attribute__((ext_vector_type(8))) short short8;
typedef __attribute__((ext_vector_type(4))) float float4v;

__device__ __forceinline__ unsigned short f2bf(float f) {
    unsigned int u = __float_as_uint(f);
    unsigned int r = (u + 0x7FFFu + ((u >> 16) & 1u)) >> 16;
    return (unsigned short)r;
}
__device__ __forceinline__ float fsig(float x) {
    return __builtin_amdgcn_rcpf(1.0f + __expf(-x));
}
__device__ __forceinline__ float ftanh(float x) {
    return 1.0f - 2.0f * __builtin_amdgcn_rcpf(1.0f + __expf(2.0f * x));
}

// ---------------- Kernel 1: prep — W5f fp32 frag table + hypernet m2 ----------
__global__ __launch_bounds__(256) void prep_kernel(
    const float* __restrict__ memory, const float* __restrict__ w1,
    const float* __restrict__ b1,     const float* __restrict__ w2,
    const float* __restrict__ b2,     const float* __restrict__ w3,
    const float* __restrict__ b3,     float* __restrict__ W5f,
    float* __restrict__ m2_ws)
{
    const int tid = threadIdx.x;
    const int bid = blockIdx.x;
    if (bid < 120) {
        const int id = bid * 256 + tid;     // [0, 30720) float4 slots
        const int F  = id * 4;
        const int f  = F >> 9;              // frag [0,240)
        const int r  = F & 511;
        const int lane = r >> 3;
        const int j0   = r & 7;             // 0 or 4
        const int ks = f % 3;
        const int t2 = f / 3;
        const int ct = t2 & 15;
        const int k  = t2 >> 4;             // [0,5)
        const int q = lane & 15, quad = lane >> 4;
        const int o = (ct & 3) * 64 + (ct >> 2) * 16 + q;
        const float* src = (k < 4) ? (w3 + k * W3_ROW) : b3;
        float4v v;
        #pragma unroll
        for (int jj = 0; jj < 4; ++jj) {
            const int s = ks * 32 + quad * 8 + j0 + jj;
            float x = 0.f;
            if (s < IN_SZ) {
                const int i = (s < 64) ? s + 2 : s - 64;
                x = src[i * OUT_SZ + o];
            }
            v[jj] = x;
        }
        *(float4v*)(W5f + F) = v;
    } else {
        const int n = (bid - 120) * 256 + tid;   // [0, 512)
        if (n < NNODE) {
            float memv[MEM_DIM];
            #pragma unroll
            for (int j = 0; j < MEM_DIM; ++j) memv[j] = memory[n * MEM_DIM + j];
            float mem1[MEM_DIM];
            #pragma unroll
            for (int t = 0; t < MEM_DIM; ++t) {
                float s = b1[t];
                #pragma unroll
                for (int j = 0; j < MEM_DIM; ++j) s += memv[j] * w1[j * MEM_DIM + t];
                mem1[t] = ftanh(s);
            }
            #pragma unroll
            for (int t = 0; t < BOT_DIM; ++t) {
                float s = b2[t];
                #pragma unroll
                for (int j = 0; j < MEM_DIM; ++j) s += mem1[j] * w2[j * BOT_DIM + t];
                m2_ws[n * 4 + t] = ftanh(s);
            }
        }
    }
}

// ---------------- Kernel 2: fused — combined-W in LDS + MFMA + LSTM epilogue --
// block = (n, h): 1024 blocks x 256 threads (4 waves). Wave = 32 batch rows x
// 128 cols. Combined W (24 frags, bf16) built once per block into LDS.
__global__ __launch_bounds__(256, 3) void fused_kernel(
    const float* __restrict__ inputs, const float* __restrict__ hx,
    const float* __restrict__ cx,     const float* __restrict__ b_out,
    const float* __restrict__ W5f,    const float* __restrict__ m2_ws,
    float* __restrict__ out)
{
    __shared__ unsigned short Wl[24 * 512];   // 24576 B, frag-ordered
    const int tid  = threadIdx.x;
    const unsigned bid = blockIdx.x;
    const int n    = bid >> 1;
    const int h    = bid & 1;
    const int w    = tid >> 6;
    const int lane = tid & 63;
    const int q    = lane & 15;
    const int quad = lane >> 4;

    float coef[4];
    #pragma unroll
    for (int k = 0; k < 4; ++k) coef[k] = m2_ws[n * 4 + k];

    // ---- A fragments from hx/inputs (issued early; packed below) ----
    float4v xa[2][4];
    float xin[2][2];
    #pragma unroll
    for (int rt = 0; rt < 2; ++rt) {
        const int row = w * 32 + rt * 16 + q;
        const float* hrow = hx + (size_t)row * HID + n * RU + quad * 8;
        xa[rt][0] = *(const float4v*)(hrow);
        xa[rt][1] = *(const float4v*)(hrow + 4);
        xa[rt][2] = *(const float4v*)(hrow + 32);
        xa[rt][3] = *(const float4v*)(hrow + 36);
        if (quad == 0) {
            const float* ip = inputs + (size_t)row * (NNODE * 2) + n * 2;
            xin[rt][0] = ip[0];
            xin[rt][1] = ip[1];
        } else {
            xin[rt][0] = 0.f;
            xin[rt][1] = 0.f;
        }
    }

    // ---- combined W -> LDS: 1536 chunks / 256 threads = 6 each ----
    #pragma unroll
    for (int it = 0; it < 6; ++it) {
        const int c  = it * 256 + tid;
        const int fl = c >> 6;          // local frag [0,24) = ctl*3+ks
        const int l  = c & 63;
        const int ctl = fl / 3;
        const int ks  = fl - ctl * 3;
        const float* p = W5f + (size_t)(((h * 8 + ctl) * 3 + ks) * 512) + l * 8;
        float4v r0 = *(const float4v*)(p + 4 * K_STEP);      // b3 frag
        float4v r1 = *(const float4v*)(p + 4 * K_STEP + 4);
        #pragma unroll
        for (int k = 0; k < 4; ++k) {
            r0 += coef[k] * *(const float4v*)(p + k * K_STEP);
            r1 += coef[k] * *(const float4v*)(p + k * K_STEP + 4);
        }
        short8 ov;
        ov[0] = (short)f2bf(r0[0]); ov[1] = (short)f2bf(r0[1]);
        ov[2] = (short)f2bf(r0[2]); ov[3] = (short)f2bf(r0[3]);
        ov[4] = (short)f2bf(r1[0]); ov[5] = (short)f2bf(r1[1]);
        ov[6] = (short)f2bf(r1[2]); ov[7] = (short)f2bf(r1[3]);
        *(short8*)(Wl + fl * 512 + l * 8) = ov;
    }

    // ---- epilogue operand prefetch (hides HBM latency behind barrier) ----
    float bo[2][4];
    #pragma unroll
    for (int rh = 0; rh < 2; ++rh)
        #pragma unroll
        for (int g = 0; g < 4; ++g)
            bo[rh][g] = b_out[g * 64 + (h * 2 + rh) * 16 + q];

    float cxr[2][4][2];
    #pragma unroll
    for (int rt = 0; rt < 2; ++rt)
        #pragma unroll
        for (int v = 0; v < 4; ++v) {
            const int b = w * 32 + rt * 16 + quad * 4 + v;
            #pragma unroll
            for (int rh = 0; rh < 2; ++rh)
                cxr[rt][v][rh] = cx[(size_t)b * HID + n * RU + (h * 2 + rh) * 16 + q];
        }

    // ---- pack A once (bf16) ----
    short8 a[3][2];
    #pragma unroll
    for (int rt = 0; rt < 2; ++rt) {
        #pragma unroll
        for (int ksh = 0; ksh < 2; ++ksh) {
            float4v lo = xa[rt][ksh * 2];
            float4v hi = xa[rt][ksh * 2 + 1];
            short8 t;
            t[0] = (short)f2bf(lo[0]); t[1] = (short)f2bf(lo[1]);
            t[2] = (short)f2bf(lo[2]); t[3] = (short)f2bf(lo[3]);
            t[4] = (short)f2bf(hi[0]); t[5] = (short)f2bf(hi[1]);
            t[6] = (short)f2bf(hi[2]); t[7] = (short)f2bf(hi[3]);
            a[ksh][rt] = t;
        }
        short8 t2 = {0, 0, 0, 0, 0, 0, 0, 0};
        t2[0] = (short)f2bf(xin[rt][0]);
        t2[1] = (short)f2bf(xin[rt][1]);
        a[2][rt] = t2;
    }

    float4v acc[2][8];
    #pragma unroll
    for (int rt = 0; rt < 2; ++rt)
        #pragma unroll
        for (int ctl = 0; ctl < 8; ++ctl)
            acc[rt][ctl] = (float4v){0.f, 0.f, 0.f, 0.f};

    __syncthreads();

    // ---- MFMA: 3 ks x 8 ctl x 2 rt ----
    #pragma unroll
    for (int ks = 0; ks < 3; ++ks) {
        #pragma unroll
        for (int ctl = 0; ctl < 8; ++ctl) {
            short8 bf = *(const short8*)(Wl + (ctl * 3 + ks) * 512 + lane * 8);
            acc[0][ctl] = __builtin_amdgcn_mfma_f32_16x16x32_bf16(a[ks][0], bf, acc[0][ctl], 0, 0, 0);
            acc[1][ctl] = __builtin_amdgcn_mfma_f32_16x16x32_bf16(a[ks][1], bf, acc[1][ctl], 0, 0, 0);
        }
    }

    // ---- LSTM epilogue: ctl = rh*4+g -> o = g*64 + (h*2+rh)*16 + q ----
    #pragma unroll
    for (int rt = 0; rt < 2; ++rt) {
        #pragma unroll
        for (int v = 0; v < 4; ++v) {
            const int b = w * 32 + rt * 16 + quad * 4 + v;
            const size_t base = (size_t)b * HID + n * RU;
            #pragma unroll
            for (int rh = 0; rh < 2; ++rh) {
                // reference: val = sigmoid(matmul) + b_out, THEN gate activations
                float vi = fsig(acc[rt][rh * 4 + 0][v]) + bo[rh][0];
                float vf = fsig(acc[rt][rh * 4 + 1][v]) + bo[rh][1];
                float vg = fsig(acc[rt][rh * 4 + 2][v]) + bo[rh][2];
                float vo = fsig(acc[rt][rh * 4 + 3][v]) + bo[rh][3];
                float it = fsig(vi), ft = fsig(vf);
                float gt = ftanh(vg), ot = fsig(vo);
                const size_t idx = base + (h * 2 + rh) * 16 + q;
                float cc = cxr[rt][v][rh] * ft + it * gt;
                out[idx] = ot * ftanh(cc);               // hy
                out[(size_t)BATCH * HID + idx] = cc;     // cy
            }
        }
    }
}

extern "C" void kernel_launch(void* const* d_in, const int* in_sizes, int n_in,
                              void* d_out, int out_size, void* d_ws, size_t ws_size,
                              hipStream_t stream) {
    const float* inputs = (const float*)d_in[0];
    const float* hx     = (const float*)d_in[1];
    const float* cx     = (const float*)d_in[2];
    const float* memory = (const float*)d_in[3];
    const float* w1     = (const float*)d_in[4];
    const float* b1     = (const float*)d_in[5];
    const float* w2     = (const float*)d_in[6];
    const float* b2     = (const float*)d_in[7];
    const float* w3     = (const float*)d_in[8];
    const float* b3     = (const float*)d_in[9];
    const float* b_out  = (const float*)d_in[10];
    float* out = (float*)d_out;

    float* W5f   = (float*)d_ws;
    float* m2_ws = (float*)((char*)d_ws + W5F_FLOATS * 4);

    prep_kernel<<<122, 256, 0, stream>>>(memory, w1, b1, w2, b2, w3, b3, W5f, m2_ws);
    fused_kernel<<<NNODE * 2, 256, 0, stream>>>(inputs, hx, cx, b_out, W5f, m2_ws, out);
}